// Round 16
// baseline (247.791 us; speedup 1.0000x reference)
//
#include <hip/hip_runtime.h>
#include <math.h>

#define N_NODES 10000
#define N_EDGES 320000
#define TILES 8                 // edge_mlp: 8 tiles x 32 edges per block
#define NBLK (N_EDGES / (32 * TILES))   // 1250 blocks

#define SQRT3F     1.7320508075688772f
#define INV_SQRT3F 0.5773502691896258f
#define INV_SQRT2F 0.7071067811865476f

typedef short bf16x8 __attribute__((ext_vector_type(8)));
typedef short b16x4  __attribute__((ext_vector_type(4)));
typedef float f32x4  __attribute__((ext_vector_type(4)));
typedef unsigned int u32;

static __device__ __forceinline__ unsigned short f2b(float f) {
    unsigned int u = __float_as_uint(f);
    unsigned int r = (u + 0x7fffu + ((u >> 16) & 1u)) >> 16;   // RNE
    return (unsigned short)r;
}
static __device__ __forceinline__ float b2f(unsigned short h) {
    return __uint_as_float(((unsigned int)h) << 16);
}

// direct global->LDS 16B copy (lane-linear dest)
static __device__ __forceinline__ void gl_lds16(const void* g, void* l) {
    __builtin_amdgcn_global_load_lds(
        (const __attribute__((address_space(1))) u32*)g,
        (__attribute__((address_space(3))) u32*)l,
        16, 0, 0);
}

// ---------------------------------------------------------------------------
// Kernel N: node transforms via MFMA. 32 nodes/block, 20 MFMA jobs.
// ---------------------------------------------------------------------------
__global__ __launch_bounds__(256) void nt_mfma(
    const float* __restrict__ nf,
    const float* __restrict__ Wnl0,
    const float* __restrict__ Wnl1,
    float* __restrict__ st_vt32,
    unsigned short* __restrict__ st_vt16)
{
    __shared__ __align__(16) float nf_l[32 * 160];   // 20 KB

    const int n0  = blockIdx.x * 32;
    const int tid = threadIdx.x;
    const int lane = tid & 63;
    const int wv   = tid >> 6;
    const int l15  = lane & 15;
    const int g    = lane >> 4;

    #pragma unroll
    for (int r = 0; r < 5; ++r) {
        int idx = tid + r * 256;
        int row = idx / 40, off = idx - row * 40;
        int n = min(n0 + row, N_NODES - 1);
        *reinterpret_cast<f32x4*>(&nf_l[row * 160 + off * 4]) =
            *reinterpret_cast<const f32x4*>(nf + (size_t)n * 160 + off * 4);
    }
    __syncthreads();

    #pragma unroll
    for (int jj = 0; jj < 5; ++jj) {
        int job = wv * 5 + jj;              // 0..19
        f32x4 c4 = {0.f, 0.f, 0.f, 0.f};
        int colbase;
        if (job < 8) {                      // s_t
            int mt = job & 1, nt = job >> 1;
            int row = mt * 16 + l15;
            #pragma unroll
            for (int kk = 0; kk < 2; ++kk) {
                int k0 = kk * 32 + g * 8;
                bf16x8 a, b;
                #pragma unroll
                for (int j = 0; j < 8; ++j) {
                    a[j] = (short)f2b(nf_l[row * 160 + k0 + j]);
                    b[j] = (short)f2b(Wnl0[(k0 + j) * 64 + nt * 16 + l15]);
                }
                c4 = __builtin_amdgcn_mfma_f32_16x16x32_bf16(a, b, c4, 0, 0, 0);
            }
            colbase = nt * 16 + l15;
            #pragma unroll
            for (int r = 0; r < 4; ++r) {
                int rr = mt * 16 + g * 4 + r;
                int n = n0 + rr;
                if (n < N_NODES) {
                    st_vt32[(size_t)n * 160 + colbase] = c4[r];
                    st_vt16[(size_t)n * 160 + colbase] = f2b(c4[r]);
                }
            }
        } else {                            // v_t
            int j2 = job - 8;
            int i = j2 >> 2, nt = (j2 >> 1) & 1, mt = j2 & 1;
            int row = mt * 16 + l15;
            bf16x8 a, b;
            #pragma unroll
            for (int j = 0; j < 8; ++j) {
                int k = g * 8 + j;
                a[j] = (short)f2b(nf_l[row * 160 + 64 + k * 3 + i]);
                b[j] = (short)f2b(Wnl1[k * 32 + nt * 16 + l15]);
            }
            c4 = __builtin_amdgcn_mfma_f32_16x16x32_bf16(a, b, c4, 0, 0, 0);
            colbase = 64 + i * 32 + nt * 16 + l15;
            #pragma unroll
            for (int r = 0; r < 4; ++r) {
                int rr = mt * 16 + g * 4 + r;
                int n = n0 + rr;
                if (n < N_NODES) {
                    st_vt32[(size_t)n * 160 + colbase] = c4[r];
                    st_vt16[(size_t)n * 160 + colbase] = f2b(c4[r]);
                }
            }
        }
    }
}

// ---------------------------------------------------------------------------
// Kernel P: merged prep (histogram + weight conversions).
// ---------------------------------------------------------------------------
__global__ __launch_bounds__(256) void prep_kernel(
    const float* __restrict__ Wfc1,
    const float* __restrict__ Wfc2,
    const float* __restrict__ Wout_s,
    const float* __restrict__ Wout_v,
    const float* __restrict__ Wskip0,
    const float* __restrict__ Wskip1,
    const int* __restrict__ eidx,
    unsigned short* __restrict__ W1T,
    unsigned short* __restrict__ W2T,
    unsigned short* __restrict__ WsCombT,
    unsigned short* __restrict__ WvCombT,
    int* __restrict__ cnt)
{
    const int b = blockIdx.x;
    const int tid = threadIdx.x;
    if (b < 1250) {
        int e = b * 256 + tid;
        if (e < N_EDGES) atomicAdd(&cnt[eidx[e]], 1);
    } else if (b < 1322) {
        int idx = (b - 1250) * 256 + tid;
        if (idx < 4096) {
            int n = idx >> 6, k = idx & 63;
            W1T[idx] = f2b(Wfc1[k * 64 + n]);
        } else if (idx < 18432) {
            int j = idx - 4096;
            int n = j >> 6, k = j & 63;
            W2T[j] = f2b(Wfc2[k * 224 + n]);
        }
    } else {
        int idx = (b - 1322) * 256 + tid;
        if (idx < 15360) {
            int n = idx / 160, k = idx - n * 160;
            float v = (k < 96) ? Wout_s[k * 96 + n] : Wskip0[(k - 96) * 96 + n];
            WsCombT[idx] = f2b(v);
        } else if (idx < 20480) {
            int j = idx - 15360;
            int n = j / 160, k = j - n * 160;
            float v = (k < 128) ? Wout_v[k * 32 + n] : Wskip1[(k - 128) * 32 + n];
            WvCombT[j] = f2b(v);
        }
    }
}

// ---------------------------------------------------------------------------
// scan + scatter (sorting by src)
// ---------------------------------------------------------------------------
__global__ __launch_bounds__(1024) void scan_kernel(
    const int* __restrict__ cnt, int* __restrict__ row_start)
{
    __shared__ int part[1024];
    const int t = threadIdx.x;
    const int CH = 10;
    int base = t * CH;
    int s = 0;
    for (int i = 0; i < CH; ++i) {
        int idx = base + i;
        if (idx < N_NODES) s += cnt[idx];
    }
    part[t] = s;
    __syncthreads();
    for (int off = 1; off < 1024; off <<= 1) {
        int v = (t >= off) ? part[t - off] : 0;
        __syncthreads();
        part[t] += v;
        __syncthreads();
    }
    int run = (t == 0) ? 0 : part[t - 1];
    for (int i = 0; i < CH; ++i) {
        int idx = base + i;
        if (idx < N_NODES) { row_start[idx] = run; run += cnt[idx]; }
    }
    if (t == 1023) row_start[N_NODES] = run;
}

__global__ __launch_bounds__(256) void scatter_kernel(
    const int* __restrict__ eidx, const float* __restrict__ edge_attr,
    const int* __restrict__ row_start,
    int* __restrict__ fill, int* __restrict__ order,
    int* __restrict__ src_srt, int* __restrict__ dst_srt,
    float* __restrict__ sh_srt)
{
    int e = blockIdx.x * 256 + threadIdx.x;
    if (e >= N_EDGES) return;
    int s = eidx[e];
    int p = atomicAdd(&fill[s], 1) + row_start[s];
    order[p] = e;
    src_srt[p] = s;
    dst_srt[p] = eidx[N_EDGES + e];
    float x = edge_attr[(size_t)e * 3 + 0];
    float y = edge_attr[(size_t)e * 3 + 1];
    float z = edge_attr[(size_t)e * 3 + 2];
    float inv = SQRT3F / sqrtf(x * x + y * y + z * z);
    sh_srt[(size_t)p * 4 + 0] = x * inv;
    sh_srt[(size_t)p * 4 + 1] = y * inv;
    sh_srt[(size_t)p * 4 + 2] = z * inv;
    sh_srt[(size_t)p * 4 + 3] = 0.f;
}

// ---------------------------------------------------------------------------
// Kernel A: pure MFMA MLP pipeline. Writes w_srt[p][224] bf16 coalesced.
// ---------------------------------------------------------------------------
__global__ __launch_bounds__(256, 7) void edge_mlp(
    const unsigned short* __restrict__ W1T,
    const unsigned short* __restrict__ W2T,
    const int* __restrict__ order,
    const float* __restrict__ edge_feature,
    unsigned short* __restrict__ w_srt)
{
    __shared__ __align__(16) unsigned short A1[32 * 64];      // 4 KB (swizzled)
    __shared__ __align__(16) unsigned short Hs[32 * 64];      // 4 KB (swizzled)
    __shared__ __align__(16) unsigned short w_s[32 * 224];    // 14 KB
    __shared__ int eid_s[32 * TILES];

    const int tid  = threadIdx.x;
    const int lane = tid & 63;
    const int wv   = tid >> 6;
    const int l15  = lane & 15;
    const int g    = lane >> 4;
    const int p0   = blockIdx.x * (32 * TILES);

    bf16x8 w1b0 = *reinterpret_cast<const bf16x8*>(&W1T[(wv * 16 + l15) * 64 + g * 8]);
    bf16x8 w1b1 = *reinterpret_cast<const bf16x8*>(&W1T[(wv * 16 + l15) * 64 + 32 + g * 8]);
    bf16x8 w2b0[4], w2b1[4];
    #pragma unroll
    for (int ii = 0; ii < 4; ++ii) {
        int nt = wv * 4 + ii;
        w2b0[ii] = *reinterpret_cast<const bf16x8*>(&W2T[(nt * 16 + l15) * 64 + g * 8]);
        w2b1[ii] = *reinterpret_cast<const bf16x8*>(&W2T[(nt * 16 + l15) * 64 + 32 + g * 8]);
    }

    if (tid < 32 * TILES) eid_s[tid] = order[p0 + tid];
    __syncthreads();

    f32x4 efr[2];
    auto load_ef = [&](int t) {
        int ebase = t * 32;
        #pragma unroll
        for (int r = 0; r < 2; ++r) {
            int q = tid + r * 256;
            int el = q >> 4, qf = q & 15;
            efr[r] = *reinterpret_cast<const f32x4*>(
                edge_feature + (size_t)eid_s[ebase + el] * 64 + qf * 4);
        }
    };
    auto write_ef = [&]() {
        #pragma unroll
        for (int r = 0; r < 2; ++r) {
            int q = tid + r * 256;
            int el = q >> 4, f0 = (q & 15) * 4;
            b16x4 h;
            #pragma unroll
            for (int j = 0; j < 4; ++j) h[j] = (short)f2b(efr[r][j]);
            *reinterpret_cast<b16x4*>(&A1[el * 64 + (f0 ^ ((el & 7) << 3))]) = h;
        }
    };

    load_ef(0);

    for (int t = 0; t < TILES; ++t) {
        write_ef();
        __syncthreads();
        if (t < TILES - 1) load_ef(t + 1);

        // GEMM1: Hs = relu(A1 @ Wfc1)
        {
            const int nt = wv;
            #pragma unroll
            for (int mt = 0; mt < 2; ++mt) {
                f32x4 c4 = {0.f, 0.f, 0.f, 0.f};
                int ra = mt * 16 + l15;
                int sw = (ra & 7) << 3;
                bf16x8 a0 = *reinterpret_cast<const bf16x8*>(&A1[ra * 64 + ((g * 8) ^ sw)]);
                bf16x8 a1 = *reinterpret_cast<const bf16x8*>(&A1[ra * 64 + ((32 + g * 8) ^ sw)]);
                c4 = __builtin_amdgcn_mfma_f32_16x16x32_bf16(a0, w1b0, c4, 0, 0, 0);
                c4 = __builtin_amdgcn_mfma_f32_16x16x32_bf16(a1, w1b1, c4, 0, 0, 0);
                #pragma unroll
                for (int r = 0; r < 4; ++r) {
                    int row = mt * 16 + g * 4 + r;
                    int col = nt * 16 + l15;
                    Hs[row * 64 + (col ^ ((row & 7) << 3))] = f2b(fmaxf(c4[r], 0.f));
                }
            }
        }
        __syncthreads();

        // GEMM2: w_s = Hs @ Wfc2 (stores masked nt<14)
        {
            #pragma unroll
            for (int ii = 0; ii < 4; ++ii) {
                int nt = wv * 4 + ii;
                #pragma unroll
                for (int mt = 0; mt < 2; ++mt) {
                    f32x4 c4 = {0.f, 0.f, 0.f, 0.f};
                    int ra = mt * 16 + l15;
                    int sw = (ra & 7) << 3;
                    bf16x8 a0 = *reinterpret_cast<const bf16x8*>(&Hs[ra * 64 + ((g * 8) ^ sw)]);
                    bf16x8 a1 = *reinterpret_cast<const bf16x8*>(&Hs[ra * 64 + ((32 + g * 8) ^ sw)]);
                    c4 = __builtin_amdgcn_mfma_f32_16x16x32_bf16(a0, w2b0[ii], c4, 0, 0, 0);
                    c4 = __builtin_amdgcn_mfma_f32_16x16x32_bf16(a1, w2b1[ii], c4, 0, 0, 0);
                    if (nt < 14) {
                        #pragma unroll
                        for (int r = 0; r < 4; ++r) {
                            int row = mt * 16 + g * 4 + r;
                            w_s[row * 224 + nt * 16 + l15] = f2b(c4[r]);
                        }
                    }
                }
            }
        }
        __syncthreads();

        // coalesced copy-out: 32x224 u16 = 896 x 16B
        {
            const size_t gbase = (size_t)(p0 + t * 32) * 224;
            for (int idx = tid; idx < 896; idx += 256) {
                *reinterpret_cast<f32x4*>(&w_srt[gbase + idx * 8]) =
                    *reinterpret_cast<const f32x4*>(&w_s[idx * 8]);
            }
        }
    }
}

// ---------------------------------------------------------------------------
// Kernel B: per-NODE messages (round-11 v3, best measured: ~92 us).
// One node/block; df f32 staged via global_load_lds (unmasked, clamped);
// w read directly from global (stream-once rows); agg written coalesced.
// LDS ~23 KB -> 7 blocks/CU.
// ---------------------------------------------------------------------------
__global__ __launch_bounds__(256, 7) void node_msg(
    const int* __restrict__ row_start,
    const int* __restrict__ dst_srt,
    const float* __restrict__ sh_srt,
    const unsigned short* __restrict__ w_srt,
    const float* __restrict__ st_vt32,
    float* __restrict__ agg)
{
    __shared__ __align__(16) float df[32 * 160];   // 20480 B (f32)
    __shared__ float aggbuf[480];
    __shared__ float sh_c[32][4];

    // chunked XCD remap (10000 = 8 * 1250)
    const int n   = (blockIdx.x & 7) * 1250 + (blockIdx.x >> 3);
    const int tid = threadIdx.x;
    const int p_start = row_start[n];
    const int p_end   = row_start[n + 1];

    const int tid2 = tid & 127;
    const int half = tid >> 7;
    int region, cb, iv;
    if (tid2 < 48)       { region = 0; cb = tid2 & 15;        iv = tid2 >> 4; }
    else if (tid2 < 64)  { region = 1; cb = tid2 - 48;        iv = 0; }
    else if (tid2 < 88)  { region = 2; cb = (tid2 - 64) & 7;  iv = (tid2 - 64) >> 3; }
    else if (tid2 < 112) { region = 3; cb = (tid2 - 88) & 7;  iv = (tid2 - 88) >> 3; }
    else if (tid2 < 120) { region = 4; cb = tid2 - 112;       iv = 0; }
    else                 { region = 5; cb = 0; iv = 0; }
    int rbase = 0, woff = 0, doff = 0;
    if (region == 0)      { rbase = 96 + iv * 64 + 4 * cb;  woff = 64 + 4 * cb;  doff = 4 * cb; }
    else if (region == 1) { rbase = 4 * cb;                 woff = 4 * cb;       doff = 4 * cb; }
    else if (region == 2) { rbase = 288 + iv * 32 + 4 * cb; woff = 128 + 4 * cb; doff = 64 + iv * 32 + 4 * cb; }
    else if (region == 3) { rbase = 384 + iv * 32 + 4 * cb; woff = 192 + 4 * cb; }
    else if (region == 4) { rbase = 64 + 4 * cb;            woff = 160 + 4 * cb; }
    int i1 = iv + 1; if (i1 == 3) i1 = 0;
    int i2 = 3 - iv - i1;

    f32x4 acc = {0.f, 0.f, 0.f, 0.f};

    for (int pb = p_start; pb < p_end; pb += 32) {
        __syncthreads();                       // df/sh_c reuse guard

        if (tid < 32) {
            int pp = min(pb + tid, p_end - 1);
            *reinterpret_cast<f32x4*>(&sh_c[tid][0]) =
                *reinterpret_cast<const f32x4*>(&sh_srt[(size_t)pp * 4]);
        }
        // stage df f32: 1280 x 16B (5 full rounds of 256, clamped)
        #pragma unroll
        for (int r = 0; r < 5; ++r) {
            int idx = tid + r * 256;
            int el = idx / 40, off = idx - el * 40;
            int pp = min(pb + el, p_end - 1);
            int d = dst_srt[pp];
            gl_lds16(st_vt32 + (size_t)d * 160 + off * 4, &df[idx * 4]);
        }
        __syncthreads();                       // vmcnt drained

        const int nvalid = p_end - pb;
        if (region < 5) {
            const int e0l = half * 16;
            #pragma unroll 4
            for (int j2 = 0; j2 < 16; ++j2) {
                int el = e0l + j2;
                if (el >= nvalid) break;       // uniform per half
                const float* dfp = &df[el * 160];
                const unsigned short* we = w_srt + (size_t)(pb + el) * 224;  // GLOBAL
                b16x4 w = *reinterpret_cast<const b16x4*>(we + woff);
                if (region == 0) {
                    f32x4 x = *reinterpret_cast<const f32x4*>(dfp + doff);
                    float sh = sh_c[el][iv];
                    #pragma unroll
                    for (int j = 0; j < 4; ++j)
                        acc[j] += b2f((unsigned short)w[j]) * x[j] * sh;
                } else if (region == 1 || region == 2) {
                    f32x4 x = *reinterpret_cast<const f32x4*>(dfp + doff);
                    #pragma unroll
                    for (int j = 0; j < 4; ++j)
                        acc[j] += b2f((unsigned short)w[j]) * x[j];
                } else if (region == 3) {
                    f32x4 xA = *reinterpret_cast<const f32x4*>(dfp + 64 + i1 * 32 + 4 * cb);
                    f32x4 xB = *reinterpret_cast<const f32x4*>(dfp + 64 + i2 * 32 + 4 * cb);
                    float shA = sh_c[el][i1], shB = sh_c[el][i2];
                    #pragma unroll
                    for (int j = 0; j < 4; ++j)
                        acc[j] += b2f((unsigned short)w[j]) *
                                  (xA[j] * shB - xB[j] * shA) * INV_SQRT2F;
                } else {
                    f32x4 x0 = *reinterpret_cast<const f32x4*>(dfp + 64 + 4 * cb);
                    f32x4 x1 = *reinterpret_cast<const f32x4*>(dfp + 96 + 4 * cb);
                    f32x4 x2 = *reinterpret_cast<const f32x4*>(dfp + 128 + 4 * cb);
                    float s0 = sh_c[el][0], s1 = sh_c[el][1], s2 = sh_c[el][2];
                    #pragma unroll
                    for (int j = 0; j < 4; ++j)
                        acc[j] += b2f((unsigned short)w[j]) *
                                  (x0[j] * s0 + x1[j] * s1 + x2[j] * s2) * INV_SQRT3F;
                }
            }
        }
    }

    // combine halves into aggbuf, write agg coalesced
    __syncthreads();
    if (half == 0 && region < 5) {
        #pragma unroll
        for (int j = 0; j < 4; ++j) aggbuf[rbase + j] = acc[j];
    }
    __syncthreads();
    if (half == 1 && region < 5) {
        #pragma unroll
        for (int j = 0; j < 4; ++j) aggbuf[rbase + j] += acc[j];
    }
    __syncthreads();
    if (tid < 120) {
        *reinterpret_cast<f32x4*>(&agg[(size_t)n * 480 + tid * 4]) =
            *reinterpret_cast<const f32x4*>(&aggbuf[tid * 4]);
    }
}

// ---------------------------------------------------------------------------
// Kernel C: out_gemm. 32 nodes/block, MFMA K=160 fused output transforms,
// then silu/sigmoid-gate epilogue, final out[n][160].
// ---------------------------------------------------------------------------
__global__ __launch_bounds__(256) void out_gemm(
    const float* __restrict__ agg,
    const float* __restrict__ nf,
    const unsigned short* __restrict__ WsCombT,
    const unsigned short* __restrict__ WvCombT,
    float* __restrict__ out)
{
    __shared__ float os_l[32][96];       // 12 KB
    __shared__ float ov_l[3][32][32];    // 12 KB

    const int n0  = blockIdx.x * 32;
    const int tid = threadIdx.x;
    const int lane = tid & 63;
    const int wv   = tid >> 6;
    const int l15  = lane & 15;
    const int g    = lane >> 4;

    #pragma unroll
    for (int jj = 0; jj < 6; ++jj) {
        int job = wv * 6 + jj;          // 0..23
        bool isS;
        int mt, nt, ii = 0;
        if (job < 12) { isS = true;  mt = job & 1; nt = job >> 1; }
        else { int j = job - 12; isS = false; ii = j >> 2; mt = (j >> 1) & 1; nt = j & 1; }

        int ra = mt * 16 + l15;
        int n  = min(n0 + ra, N_NODES - 1);
        const float* aggn = agg + (size_t)n * 480;
        const float* nfn  = nf + (size_t)n * 160;
        const unsigned short* WT = isS ? WsCombT : WvCombT;

        f32x4 c4 = {0.f, 0.f, 0.f, 0.f};
        #pragma unroll
        for (int kk = 0; kk < 5; ++kk) {
            int k0 = kk * 32 + g * 8;
            float av[8];
            if (isS) {
                if (k0 < 96) {
                    f32x4 p0 = *reinterpret_cast<const f32x4*>(aggn + k0);
                    f32x4 p1 = *reinterpret_cast<const f32x4*>(aggn + k0 + 4);
                    #pragma unroll
                    for (int j = 0; j < 4; ++j) { av[j] = p0[j] * (1.f/32.f); av[4+j] = p1[j] * (1.f/32.f); }
                } else {
                    f32x4 p0 = *reinterpret_cast<const f32x4*>(nfn + (k0 - 96));
                    f32x4 p1 = *reinterpret_cast<const f32x4*>(nfn + (k0 - 96) + 4);
                    #pragma unroll
                    for (int j = 0; j < 4; ++j) { av[j] = p0[j]; av[4+j] = p1[j]; }
                }
            } else {
                if (k0 < 128) {
                    int base = (k0 < 64) ? (96 + ii * 64 + k0)
                             : (k0 < 96) ? (288 + ii * 32 + (k0 - 64))
                                         : (384 + ii * 32 + (k0 - 96));
                    f32x4 p0 = *reinterpret_cast<const f32x4*>(aggn + base);
                    f32x4 p1 = *reinterpret_cast<const f32x4*>(aggn + base + 4);
                    #pragma unroll
                    for (int j = 0; j < 4; ++j) { av[j] = p0[j] * (1.f/32.f); av[4+j] = p1[j] * (1.f/32.f); }
                } else {
                    #pragma unroll
                    for (int j = 0; j < 8; ++j)
                        av[j] = nfn[64 + (k0 - 128 + j) * 3 + ii];
                }
            }
            bf16x8 a;
            #pragma unroll
            for (int j = 0; j < 8; ++j) a[j] = (short)f2b(av[j]);
            bf16x8 bfr = *reinterpret_cast<const bf16x8*>(
                WT + (size_t)(nt * 16 + l15) * 160 + k0);
            c4 = __builtin_amdgcn_mfma_f32_16x16x32_bf16(a, bfr, c4, 0, 0, 0);
        }
        #pragma unroll
        for (int r = 0; r < 4; ++r) {
            int row = mt * 16 + g * 4 + r;
            int col = nt * 16 + l15;
            if (isS) os_l[row][col] = c4[r];
            else     ov_l[ii][row][col] = c4[r];
        }
    }
    __syncthreads();

    for (int idx = tid; idx < 32 * 160; idx += 256) {
        int r = idx / 160, c = idx - r * 160;
        int n = n0 + r;
        if (n < N_NODES) {
            if (c < 64) {
                float x = os_l[r][c];
                out[(size_t)n * 160 + c] = x / (1.f + expf(-x));      // silu
            } else {
                int t = c - 64;
                int k = t / 3, i = t - 3 * k;
                float gg = os_l[r][64 + k];
                gg = 1.f / (1.f + expf(-gg));                          // sigmoid
                out[(size_t)n * 160 + c] = gg * ov_l[i][r][k];
            }
        }
    }
}

// ---------------------------------------------------------------------------
// Fallback path (only if ws can't hold w_srt): fused kernel + out.
// ---------------------------------------------------------------------------
__global__ __launch_bounds__(256, 3) void edge_conv_fused(
    const unsigned short* __restrict__ W1T,
    const unsigned short* __restrict__ W2T,
    const int* __restrict__ order,
    const int* __restrict__ src_srt,
    const int* __restrict__ dst_srt,
    const float* __restrict__ sh_srt,
    const float* __restrict__ edge_feature,
    const unsigned short* __restrict__ st_vt16,
    float* __restrict__ agg)
{
    __shared__ __align__(16) unsigned short A1[32 * 64];
    __shared__ __align__(16) unsigned short Hs[32 * 64];
    __shared__ __align__(16) unsigned short w_s[32 * 224];
    __shared__ __align__(16) unsigned short df[2][32 * 160];
    __shared__ int   eid_s[32 * TILES];
    __shared__ int   src_s[32 * TILES];
    __shared__ int   dst_s[32 * TILES];
    __shared__ float sh_s[32 * TILES][4];

    const int tid  = threadIdx.x;
    const int lane = tid & 63;
    const int wv   = tid >> 6;
    const int l15  = lane & 15;
    const int g    = lane >> 4;
    const int p0   = blockIdx.x * (32 * TILES);

    bf16x8 w1b0 = *reinterpret_cast<const bf16x8*>(&W1T[(wv * 16 + l15) * 64 + g * 8]);
    bf16x8 w1b1 = *reinterpret_cast<const bf16x8*>(&W1T[(wv * 16 + l15) * 64 + 32 + g * 8]);
    bf16x8 w2b0[4], w2b1[4];
    #pragma unroll
    for (int ii = 0; ii < 4; ++ii) {
        int nt = wv * 4 + ii;
        w2b0[ii] = *reinterpret_cast<const bf16x8*>(&W2T[(nt * 16 + l15) * 64 + g * 8]);
        w2b1[ii] = *reinterpret_cast<const bf16x8*>(&W2T[(nt * 16 + l15) * 64 + 32 + g * 8]);
    }

    for (int b = tid; b < 32 * TILES; b += 256) {
        int p = p0 + b;
        eid_s[b] = order[p];
        src_s[b] = src_srt[p];
        dst_s[b] = dst_srt[p];
        *reinterpret_cast<f32x4*>(&sh_s[b][0]) =
            *reinterpret_cast<const f32x4*>(&sh_srt[(size_t)p * 4]);
    }
    __syncthreads();

    const int tid2 = tid & 127;
    int region, cb, iv;
    if (tid2 < 48)       { region = 0; cb = tid2 & 15;        iv = tid2 >> 4; }
    else if (tid2 < 64)  { region = 1; cb = tid2 - 48;        iv = 0; }
    else if (tid2 < 88)  { region = 2; cb = (tid2 - 64) & 7;  iv = (tid2 - 64) >> 3; }
    else if (tid2 < 112) { region = 3; cb = (tid2 - 88) & 7;  iv = (tid2 - 88) >> 3; }
    else if (tid2 < 120) { region = 4; cb = tid2 - 112;       iv = 0; }
    else                 { region = 5; cb = 0; iv = 0; }
    int rbase = 0, woff = 0, doff = 0;
    if (region == 0)      { rbase = 96 + iv * 64 + 4 * cb;  woff = 64 + 4 * cb;  doff = 4 * cb; }
    else if (region == 1) { rbase = 4 * cb;                 woff = 4 * cb;       doff = 4 * cb; }
    else if (region == 2) { rbase = 288 + iv * 32 + 4 * cb; woff = 128 + 4 * cb; doff = 64 + iv * 32 + 4 * cb; }
    else if (region == 3) { rbase = 384 + iv * 32 + 4 * cb; woff = 192 + 4 * cb; }
    else if (region == 4) { rbase = 64 + 4 * cb;            woff = 160 + 4 * cb; }
    int i1 = iv + 1; if (i1 == 3) i1 = 0;
    int i2 = 3 - iv - i1;

    f32x4 acc = {0.f, 0.f, 0.f, 0.f};
    int cur = src_s[(tid >> 7) * 16];

    f32x4 efr[2];
    auto load_ef = [&](int t) {
        int ebase = t * 32;
        #pragma unroll
        for (int r = 0; r < 2; ++r) {
            int q = tid + r * 256;
            int el = q >> 4, qf = q & 15;
            efr[r] = *reinterpret_cast<const f32x4*>(
                edge_feature + (size_t)eid_s[ebase + el] * 64 + qf * 4);
        }
    };
    auto write_ef = [&]() {
        #pragma unroll
        for (int r = 0; r < 2; ++r) {
            int q = tid + r * 256;
            int el = q >> 4, f0 = (q & 15) * 4;
            b16x4 h;
            #pragma unroll
            for (int j = 0; j < 4; ++j) h[j] = (short)f2b(efr[r][j]);
            *reinterpret_cast<b16x4*>(&A1[el * 64 + (f0 ^ ((el & 7) << 3))]) = h;
        }
    };
    auto issue_df = [&](int t, int b) {
        int ebase = t * 32;
        #pragma unroll
        for (int r = 0; r < 3; ++r) {
            int idx = tid + r * 256;
            if (idx < 640) {
                int el = idx / 20, off = idx - el * 20;
                gl_lds16(st_vt16 + (size_t)dst_s[ebase + el] * 160 + off * 8,
                         &df[b][idx * 8]);
            }
        }
    };

    issue_df(0, 0);
    load_ef(0);

    for (int t = 0; t < TILES; ++t) {
        const int b = t & 1;
        write_ef();
        __syncthreads();
        if (t < TILES - 1) {
            issue_df(t + 1, b ^ 1);
            load_ef(t + 1);
        }
        {
            const int nt = wv;
            #pragma unroll
            for (int mt = 0; mt < 2; ++mt) {
                f32x4 c4 = {0.f, 0.f, 0.f, 0.f};
                int ra = mt * 16 + l15;
                int sw = (ra & 7) << 3;
                bf16x8 a0 = *reinterpret_cast<const bf16x8*>(&A1[ra * 64 + ((g * 8) ^ sw)]);
                bf16x8 a1 = *reinterpret_cast<const bf16x8*>(&A1[ra * 64 + ((32 + g * 8) ^ sw)]);
                c4 = __builtin_amdgcn_mfma_f32_16x16x32_bf16(a0, w1b0, c4, 0, 0, 0);
                c4 = __builtin_amdgcn_mfma_f32_16x16x32_bf16(a1, w1b1, c4, 0, 0, 0);
                #pragma unroll
                for (int r = 0; r < 4; ++r) {
                    int row = mt * 16 + g * 4 + r;
                    int col = nt * 16 + l15;
                    Hs[row * 64 + (col ^ ((row & 7) << 3))] = f2b(fmaxf(c4[r], 0.f));
                }
            }
        }
        __syncthreads();
        {
            #pragma unroll
            for (int ii = 0; ii < 4; ++ii) {
                int nt = wv * 4 + ii;
                #pragma unroll
                for (int mt = 0; mt < 2; ++mt) {
                    f32x4 c4 = {0.f, 0.f, 0.f, 0.f};
                    int ra = mt * 16 + l15;
                    int sw = (ra & 7) << 3;
                    bf16x8 a0 = *reinterpret_cast<const bf16x8*>(&Hs[ra * 64 + ((g * 8) ^ sw)]);
                    bf16x8 a1 = *reinterpret_cast<const bf16x8*>(&Hs[ra * 64 + ((32 + g * 8) ^ sw)]);
                    c4 = __builtin_amdgcn_mfma_f32_16x16x32_bf16(a0, w2b0[ii], c4, 0, 0, 0);
                    c4 = __builtin_amdgcn_mfma_f32_16x16x32_bf16(a1, w2b1[ii], c4, 0, 0, 0);
                    if (nt < 14) {
                        #pragma unroll
                        for (int r = 0; r < 4; ++r) {
                            int row = mt * 16 + g * 4 + r;
                            w_s[row * 224 + nt * 16 + l15] = f2b(c4[r]);
                        }
                    }
                }
            }
        }
        __syncthreads();
        if (region < 5) {
            const int e0l = (tid >> 7) * 16;
            #pragma unroll 4
            for (int j2 = 0; j2 < 16; ++j2) {
                int el = e0l + j2;
                int eg = t * 32 + el;
                int s = src_s[eg];
                if (s != cur) {
                    #pragma unroll
                    for (int j = 0; j < 4; ++j)
                        atomicAdd(&agg[(size_t)cur * 480 + rbase + j], acc[j]);
                    acc = (f32x4){0.f, 0.f, 0.f, 0.f};
                    cur = s;
                }
                const unsigned short* dfp = &df[b][el * 160];
                const unsigned short* we  = &w_s[el * 224];
                b16x4 w = *reinterpret_cast<const b16x4*>(we + woff);
                if (region == 0) {
                    b16x4 x = *reinterpret_cast<const b16x4*>(dfp + doff);
                    float sh = sh_s[eg][iv];
                    #pragma unroll
                    for (int j = 0; j < 4; ++j)
                        acc[j] += b2f((unsigned short)w[j]) * b2f((unsigned short)x[j]) * sh;
                } else if (region == 1 || region == 2) {
                    b16x4 x = *reinterpret_cast<const b16x4*>(dfp + doff);
                    #pragma unroll
                    for (int j = 0; j < 4; ++j)
                        acc[j] += b2f((unsigned short)w[j]) * b2f((unsigned short)x[j]);
                } else if (region == 3) {
                    b16x4 xA = *reinterpret_cast<const b16x4*>(dfp + 64 + i1 * 32 + 4 * cb);
                    b16x4 xB = *reinterpret_cast<const b16x4*>(dfp + 64 + i2 * 32 + 4 * cb);
                    float shA = sh_s[eg][i1], shB = sh_s[eg][i2];
                    #pragma unroll
                    for (int j = 0; j < 4; ++j)
                        acc[j] += b2f((unsigned short)w[j]) *
                                  (b2f((unsigned short)xA[j]) * shB -
                                   b2f((unsigned short)xB[j]) * shA) * INV_SQRT2F;
                } else {
                    b16x4 x0 = *reinterpret_cast<const b16x4*>(dfp + 64 + 4 * cb);
                    b16x4 x1 = *reinterpret_cast<const b16x4*>(dfp + 96 + 4 * cb);
                    b16x4 x2 = *reinterpret_cast<const b16x4*>(dfp + 128 + 4 * cb);
                    float s0 = sh_s[eg][0], s1 = sh_s[eg][1], s2 = sh_s[eg][2];
                    #pragma unroll
                    for (int j = 0; j < 4; ++j)
                        acc[j] += b2f((unsigned short)w[j]) *
                                  (b2f((unsigned short)x0[j]) * s0 +
                                   b2f((unsigned short)x1[j]) * s1 +
                                   b2f((unsigned short)x2[j]) * s2) * INV_SQRT3F;
                }
            }
        }
    }
    if (region < 5) {
        #pragma unroll
        for (int j = 0; j < 4; ++j)
            atomicAdd(&agg[(size_t)cur * 480 + rbase + j], acc[j]);
    }
}

__global__ __launch_bounds__(128) void out_kernel(
    const float* __restrict__ agg,
    const float* __restrict__ nf,
    const float* __restrict__ Wskip0,
    const float* __restrict__ Wskip1,
    const float* __restrict__ Wout_s,
    const float* __restrict__ Wout_v,
    float* __restrict__ out)
{
    __shared__ float aggl[480];
    __shared__ float os_s[96];
    const int n = blockIdx.x;
    const int tid = threadIdx.x;
    const float* nfn = nf + (size_t)n * 160;

    for (int idx = tid; idx < 480; idx += 128)
        aggl[idx] = agg[(size_t)n * 480 + idx] * (1.f / 32.f);
    __syncthreads();

    if (tid < 96) {
        float acc = 0.f;
        #pragma unroll 8
        for (int k = 0; k < 64; ++k) acc += nfn[k] * Wskip0[k * 96 + tid];
        for (int r = 0; r < 96; ++r) acc += aggl[r] * Wout_s[r * 96 + tid];
        os_s[tid] = acc;
    }
    __syncthreads();

    if (tid < 64) {
        float x = os_s[tid];
        out[(size_t)n * 160 + tid] = x / (1.f + expf(-x));
    }
    if (tid < 96) {
        int t = tid;
        int k = t / 3, i = t - 3 * k;
        float acc = 0.f;
        #pragma unroll 8
        for (int m = 0; m < 32; ++m) acc += nfn[64 + m * 3 + i] * Wskip1[m * 32 + k];
        #pragma unroll 8
        for (int m = 0; m < 64; ++m) acc += aggl[96 + i * 64 + m] * Wout_v[m * 32 + k];
        #pragma unroll 8
        for (int m = 0; m < 32; ++m) acc += aggl[288 + i * 32 + m] * Wout_v[(64 + m) * 32 + k];
        #pragma unroll 8
        for (int m = 0; m < 32; ++m) acc += aggl[384 + i * 32 + m] * Wout_v[(96 + m) * 32 + k];
        float g = os_s[64 + k];
        g = 1.f / (1.f + expf(-g));
        out[(size_t)n * 160 + 64 + t] = g * acc;
    }
}

// ---------------------------------------------------------------------------
extern "C" void kernel_launch(void* const* d_in, const int* in_sizes, int n_in,
                              void* d_out, int out_size, void* d_ws, size_t ws_size,
                              hipStream_t stream)
{
    const float* nf     = (const float*)d_in[0];
    const float* ea     = (const float*)d_in[1];
    const float* ef     = (const float*)d_in[2];
    const float* Wskip0 = (const float*)d_in[3];
    const float* Wskip1 = (const float*)d_in[4];
    const float* Wnl0   = (const float*)d_in[5];
    const float* Wnl1   = (const float*)d_in[6];
    const float* Wfc1   = (const float*)d_in[7];
    const float* Wfc2   = (const float*)d_in[8];
    const float* Wout_s = (const float*)d_in[9];
    const float* Wout_v = (const float*)d_in[10];
    const int*   eidx   = (const int*)d_in[11];
    float* out = (float*)d_out;

    // workspace layout (16B-aligned sections)
    int*   cnt       = (int*)d_ws;                        // 10000
    int*   fill      = cnt + 10000;                       // 10000
    int*   row_start = fill + 10000;                      // 10004
    int*   order     = row_start + 10004;                 // 320000
    int*   src_srt   = order + 320000;                    // 320000
    int*   dst_srt   = src_srt + 320000;                  // 320000
    float* sh_srt    = (float*)(dst_srt + 320000);        // 1,280,000
    float* agg       = sh_srt + 1280000;                  // 4,800,000
    float* st_vt32   = agg + 4800000;                     // 1,600,000
    unsigned short* st_vt16 = (unsigned short*)(st_vt32 + 1600000); // 1,600,000
    unsigned short* W1T     = st_vt16 + 1600000;          // 4,096
    unsigned short* W2T     = W1T + 4096;                 // 16,384
    unsigned short* WsCombT = W2T + 16384;                // 15,360
    unsigned short* WvCombT = WsCombT + 15360;            // 5,120 (+pad 32)
    unsigned short* w_srt   = WvCombT + 5152;             // (N_EDGES+32)*224

    const size_t need_split =
        (size_t)((const char*)(w_srt + (size_t)(N_EDGES + 32) * 224) - (const char*)d_ws);
    const bool use_split = (ws_size >= need_split);

    hipMemsetAsync(cnt, 0, 20000 * sizeof(int), stream);   // cnt+fill

    nt_mfma<<<(N_NODES + 31) / 32, 256, 0, stream>>>(
        nf, Wnl0, Wnl1, st_vt32, st_vt16);

    prep_kernel<<<1402, 256, 0, stream>>>(
        Wfc1, Wfc2, Wout_s, Wout_v, Wskip0, Wskip1,
        eidx, W1T, W2T, WsCombT, WvCombT, cnt);

    scan_kernel<<<1, 1024, 0, stream>>>(cnt, row_start);
    scatter_kernel<<<(N_EDGES + 255) / 256, 256, 0, stream>>>(
        eidx, ea, row_start, fill, order, src_srt, dst_srt, sh_srt);

    if (use_split) {
        edge_mlp<<<NBLK, 256, 0, stream>>>(W1T, W2T, order, ef, w_srt);
        node_msg<<<N_NODES, 256, 0, stream>>>(
            row_start, dst_srt, sh_srt, w_srt, st_vt32, agg);
        out_gemm<<<(N_NODES + 31) / 32, 256, 0, stream>>>(
            agg, nf, WsCombT, WvCombT, out);
    } else {
        hipMemsetAsync(agg, 0, (size_t)N_NODES * 480 * sizeof(float), stream);
        edge_conv_fused<<<NBLK, 256, 0, stream>>>(
            W1T, W2T, order, src_srt, dst_srt, sh_srt, ef, st_vt16, agg);
        out_kernel<<<N_NODES, 128, 0, stream>>>(
            agg, nf, Wskip0, Wskip1, Wout_s, Wout_v, out);
    }
}

// Round 17
// 244.613 us; speedup vs baseline: 1.0130x; 1.0130x over previous
//
#include <hip/hip_runtime.h>
#include <math.h>

#define N_NODES 10000
#define N_EDGES 320000
#define TILES 8                 // edge_mlp: 8 tiles x 32 edges per block
#define NBLK (N_EDGES / (32 * TILES))   // 1250 blocks

#define SQRT3F     1.7320508075688772f
#define INV_SQRT3F 0.5773502691896258f
#define INV_SQRT2F 0.7071067811865476f

typedef short bf16x8 __attribute__((ext_vector_type(8)));
typedef short b16x4  __attribute__((ext_vector_type(4)));
typedef float f32x4  __attribute__((ext_vector_type(4)));
typedef unsigned int u32;

static __device__ __forceinline__ unsigned short f2b(float f) {
    unsigned int u = __float_as_uint(f);
    unsigned int r = (u + 0x7fffu + ((u >> 16) & 1u)) >> 16;   // RNE
    return (unsigned short)r;
}
static __device__ __forceinline__ float b2f(unsigned short h) {
    return __uint_as_float(((unsigned int)h) << 16);
}

// direct global->LDS 16B copy (lane-linear dest)
static __device__ __forceinline__ void gl_lds16(const void* g, void* l) {
    __builtin_amdgcn_global_load_lds(
        (const __attribute__((address_space(1))) u32*)g,
        (__attribute__((address_space(3))) u32*)l,
        16, 0, 0);
}

// ---------------------------------------------------------------------------
// Kernel P (merged): node transforms via MFMA (blocks 0..312), src histogram
// (313..1562), W1T/W2T conversion (1563..1634), WsComb/WvComb (1635..1714).
// All segments independent; single launch fills the GPU.
// ---------------------------------------------------------------------------
__global__ __launch_bounds__(256) void prep_kernel(
    const float* __restrict__ nf,
    const float* __restrict__ Wnl0,
    const float* __restrict__ Wnl1,
    const float* __restrict__ Wfc1,
    const float* __restrict__ Wfc2,
    const float* __restrict__ Wout_s,
    const float* __restrict__ Wout_v,
    const float* __restrict__ Wskip0,
    const float* __restrict__ Wskip1,
    const int* __restrict__ eidx,
    float* __restrict__ st_vt32,
    unsigned short* __restrict__ st_vt16,
    unsigned short* __restrict__ W1T,
    unsigned short* __restrict__ W2T,
    unsigned short* __restrict__ WsCombT,
    unsigned short* __restrict__ WvCombT,
    int* __restrict__ cnt)
{
    __shared__ __align__(16) float nf_l[32 * 160];   // 20 KB (nt branch only)

    const int b = blockIdx.x;
    const int tid = threadIdx.x;

    if (b < 313) {
        // ---- node transforms via MFMA: 32 nodes/block, 20 MFMA jobs ----
        const int n0  = b * 32;
        const int lane = tid & 63;
        const int wv   = tid >> 6;
        const int l15  = lane & 15;
        const int g    = lane >> 4;

        #pragma unroll
        for (int r = 0; r < 5; ++r) {
            int idx = tid + r * 256;
            int row = idx / 40, off = idx - row * 40;
            int n = min(n0 + row, N_NODES - 1);
            *reinterpret_cast<f32x4*>(&nf_l[row * 160 + off * 4]) =
                *reinterpret_cast<const f32x4*>(nf + (size_t)n * 160 + off * 4);
        }
        __syncthreads();

        #pragma unroll
        for (int jj = 0; jj < 5; ++jj) {
            int job = wv * 5 + jj;              // 0..19
            f32x4 c4 = {0.f, 0.f, 0.f, 0.f};
            int colbase;
            if (job < 8) {                      // s_t
                int mt = job & 1, nt = job >> 1;
                int row = mt * 16 + l15;
                #pragma unroll
                for (int kk = 0; kk < 2; ++kk) {
                    int k0 = kk * 32 + g * 8;
                    bf16x8 a, bb;
                    #pragma unroll
                    for (int j = 0; j < 8; ++j) {
                        a[j]  = (short)f2b(nf_l[row * 160 + k0 + j]);
                        bb[j] = (short)f2b(Wnl0[(k0 + j) * 64 + nt * 16 + l15]);
                    }
                    c4 = __builtin_amdgcn_mfma_f32_16x16x32_bf16(a, bb, c4, 0, 0, 0);
                }
                colbase = nt * 16 + l15;
                #pragma unroll
                for (int r = 0; r < 4; ++r) {
                    int rr = mt * 16 + g * 4 + r;
                    int n = n0 + rr;
                    if (n < N_NODES) {
                        st_vt32[(size_t)n * 160 + colbase] = c4[r];
                        st_vt16[(size_t)n * 160 + colbase] = f2b(c4[r]);
                    }
                }
            } else {                            // v_t
                int j2 = job - 8;
                int i = j2 >> 2, nt = (j2 >> 1) & 1, mt = j2 & 1;
                int row = mt * 16 + l15;
                bf16x8 a, bb;
                #pragma unroll
                for (int j = 0; j < 8; ++j) {
                    int k = g * 8 + j;
                    a[j]  = (short)f2b(nf_l[row * 160 + 64 + k * 3 + i]);
                    bb[j] = (short)f2b(Wnl1[k * 32 + nt * 16 + l15]);
                }
                c4 = __builtin_amdgcn_mfma_f32_16x16x32_bf16(a, bb, c4, 0, 0, 0);
                colbase = 64 + i * 32 + nt * 16 + l15;
                #pragma unroll
                for (int r = 0; r < 4; ++r) {
                    int rr = mt * 16 + g * 4 + r;
                    int n = n0 + rr;
                    if (n < N_NODES) {
                        st_vt32[(size_t)n * 160 + colbase] = c4[r];
                        st_vt16[(size_t)n * 160 + colbase] = f2b(c4[r]);
                    }
                }
            }
        }
    } else if (b < 1563) {
        int e = (b - 313) * 256 + tid;
        if (e < N_EDGES) atomicAdd(&cnt[eidx[e]], 1);
    } else if (b < 1635) {
        int idx = (b - 1563) * 256 + tid;
        if (idx < 4096) {
            int n = idx >> 6, k = idx & 63;
            W1T[idx] = f2b(Wfc1[k * 64 + n]);
        } else if (idx < 18432) {
            int j = idx - 4096;
            int n = j >> 6, k = j & 63;
            W2T[j] = f2b(Wfc2[k * 224 + n]);
        }
    } else {
        int idx = (b - 1635) * 256 + tid;
        if (idx < 15360) {
            int n = idx / 160, k = idx - n * 160;
            float v = (k < 96) ? Wout_s[k * 96 + n] : Wskip0[(k - 96) * 96 + n];
            WsCombT[idx] = f2b(v);
        } else if (idx < 20480) {
            int j = idx - 15360;
            int n = j / 160, k = j - n * 160;
            float v = (k < 128) ? Wout_v[k * 32 + n] : Wskip1[(k - 128) * 32 + n];
            WvCombT[j] = f2b(v);
        }
    }
}

// ---------------------------------------------------------------------------
// scan + scatter (sorting by src)
// ---------------------------------------------------------------------------
__global__ __launch_bounds__(1024) void scan_kernel(
    const int* __restrict__ cnt, int* __restrict__ row_start)
{
    __shared__ int part[1024];
    const int t = threadIdx.x;
    const int CH = 10;
    int base = t * CH;
    int s = 0;
    for (int i = 0; i < CH; ++i) {
        int idx = base + i;
        if (idx < N_NODES) s += cnt[idx];
    }
    part[t] = s;
    __syncthreads();
    for (int off = 1; off < 1024; off <<= 1) {
        int v = (t >= off) ? part[t - off] : 0;
        __syncthreads();
        part[t] += v;
        __syncthreads();
    }
    int run = (t == 0) ? 0 : part[t - 1];
    for (int i = 0; i < CH; ++i) {
        int idx = base + i;
        if (idx < N_NODES) { row_start[idx] = run; run += cnt[idx]; }
    }
    if (t == 1023) row_start[N_NODES] = run;
}

__global__ __launch_bounds__(256) void scatter_kernel(
    const int* __restrict__ eidx, const float* __restrict__ edge_attr,
    const int* __restrict__ row_start,
    int* __restrict__ fill, int* __restrict__ order,
    int* __restrict__ src_srt, int* __restrict__ dst_srt,
    float* __restrict__ sh_srt)
{
    int e = blockIdx.x * 256 + threadIdx.x;
    if (e >= N_EDGES) return;
    int s = eidx[e];
    int p = atomicAdd(&fill[s], 1) + row_start[s];
    order[p] = e;
    src_srt[p] = s;
    dst_srt[p] = eidx[N_EDGES + e];
    float x = edge_attr[(size_t)e * 3 + 0];
    float y = edge_attr[(size_t)e * 3 + 1];
    float z = edge_attr[(size_t)e * 3 + 2];
    float inv = SQRT3F / sqrtf(x * x + y * y + z * z);
    sh_srt[(size_t)p * 4 + 0] = x * inv;
    sh_srt[(size_t)p * 4 + 1] = y * inv;
    sh_srt[(size_t)p * 4 + 2] = z * inv;
    sh_srt[(size_t)p * 4 + 3] = 0.f;
}

// ---------------------------------------------------------------------------
// Kernel A: pure MFMA MLP pipeline. Writes w_srt[p][224] bf16 coalesced.
// ---------------------------------------------------------------------------
__global__ __launch_bounds__(256, 7) void edge_mlp(
    const unsigned short* __restrict__ W1T,
    const unsigned short* __restrict__ W2T,
    const int* __restrict__ order,
    const float* __restrict__ edge_feature,
    unsigned short* __restrict__ w_srt)
{
    __shared__ __align__(16) unsigned short A1[32 * 64];      // 4 KB (swizzled)
    __shared__ __align__(16) unsigned short Hs[32 * 64];      // 4 KB (swizzled)
    __shared__ __align__(16) unsigned short w_s[32 * 224];    // 14 KB
    __shared__ int eid_s[32 * TILES];

    const int tid  = threadIdx.x;
    const int lane = tid & 63;
    const int wv   = tid >> 6;
    const int l15  = lane & 15;
    const int g    = lane >> 4;
    const int p0   = blockIdx.x * (32 * TILES);

    bf16x8 w1b0 = *reinterpret_cast<const bf16x8*>(&W1T[(wv * 16 + l15) * 64 + g * 8]);
    bf16x8 w1b1 = *reinterpret_cast<const bf16x8*>(&W1T[(wv * 16 + l15) * 64 + 32 + g * 8]);
    bf16x8 w2b0[4], w2b1[4];
    #pragma unroll
    for (int ii = 0; ii < 4; ++ii) {
        int nt = wv * 4 + ii;
        w2b0[ii] = *reinterpret_cast<const bf16x8*>(&W2T[(nt * 16 + l15) * 64 + g * 8]);
        w2b1[ii] = *reinterpret_cast<const bf16x8*>(&W2T[(nt * 16 + l15) * 64 + 32 + g * 8]);
    }

    if (tid < 32 * TILES) eid_s[tid] = order[p0 + tid];
    __syncthreads();

    f32x4 efr[2];
    auto load_ef = [&](int t) {
        int ebase = t * 32;
        #pragma unroll
        for (int r = 0; r < 2; ++r) {
            int q = tid + r * 256;
            int el = q >> 4, qf = q & 15;
            efr[r] = *reinterpret_cast<const f32x4*>(
                edge_feature + (size_t)eid_s[ebase + el] * 64 + qf * 4);
        }
    };
    auto write_ef = [&]() {
        #pragma unroll
        for (int r = 0; r < 2; ++r) {
            int q = tid + r * 256;
            int el = q >> 4, f0 = (q & 15) * 4;
            b16x4 h;
            #pragma unroll
            for (int j = 0; j < 4; ++j) h[j] = (short)f2b(efr[r][j]);
            *reinterpret_cast<b16x4*>(&A1[el * 64 + (f0 ^ ((el & 7) << 3))]) = h;
        }
    };

    load_ef(0);

    for (int t = 0; t < TILES; ++t) {
        write_ef();
        __syncthreads();
        if (t < TILES - 1) load_ef(t + 1);

        // GEMM1: Hs = relu(A1 @ Wfc1)
        {
            const int nt = wv;
            #pragma unroll
            for (int mt = 0; mt < 2; ++mt) {
                f32x4 c4 = {0.f, 0.f, 0.f, 0.f};
                int ra = mt * 16 + l15;
                int sw = (ra & 7) << 3;
                bf16x8 a0 = *reinterpret_cast<const bf16x8*>(&A1[ra * 64 + ((g * 8) ^ sw)]);
                bf16x8 a1 = *reinterpret_cast<const bf16x8*>(&A1[ra * 64 + ((32 + g * 8) ^ sw)]);
                c4 = __builtin_amdgcn_mfma_f32_16x16x32_bf16(a0, w1b0, c4, 0, 0, 0);
                c4 = __builtin_amdgcn_mfma_f32_16x16x32_bf16(a1, w1b1, c4, 0, 0, 0);
                #pragma unroll
                for (int r = 0; r < 4; ++r) {
                    int row = mt * 16 + g * 4 + r;
                    int col = nt * 16 + l15;
                    Hs[row * 64 + (col ^ ((row & 7) << 3))] = f2b(fmaxf(c4[r], 0.f));
                }
            }
        }
        __syncthreads();

        // GEMM2: w_s = Hs @ Wfc2 (stores masked nt<14)
        {
            #pragma unroll
            for (int ii = 0; ii < 4; ++ii) {
                int nt = wv * 4 + ii;
                #pragma unroll
                for (int mt = 0; mt < 2; ++mt) {
                    f32x4 c4 = {0.f, 0.f, 0.f, 0.f};
                    int ra = mt * 16 + l15;
                    int sw = (ra & 7) << 3;
                    bf16x8 a0 = *reinterpret_cast<const bf16x8*>(&Hs[ra * 64 + ((g * 8) ^ sw)]);
                    bf16x8 a1 = *reinterpret_cast<const bf16x8*>(&Hs[ra * 64 + ((32 + g * 8) ^ sw)]);
                    c4 = __builtin_amdgcn_mfma_f32_16x16x32_bf16(a0, w2b0[ii], c4, 0, 0, 0);
                    c4 = __builtin_amdgcn_mfma_f32_16x16x32_bf16(a1, w2b1[ii], c4, 0, 0, 0);
                    if (nt < 14) {
                        #pragma unroll
                        for (int r = 0; r < 4; ++r) {
                            int row = mt * 16 + g * 4 + r;
                            w_s[row * 224 + nt * 16 + l15] = f2b(c4[r]);
                        }
                    }
                }
            }
        }
        __syncthreads();

        // coalesced copy-out: 32x224 u16 = 896 x 16B
        {
            const size_t gbase = (size_t)(p0 + t * 32) * 224;
            for (int idx = tid; idx < 896; idx += 256) {
                *reinterpret_cast<f32x4*>(&w_srt[gbase + idx * 8]) =
                    *reinterpret_cast<const f32x4*>(&w_s[idx * 8]);
            }
        }
    }
}

// ---------------------------------------------------------------------------
// Kernel B: per-NODE messages (round-11 v3, best measured: ~92 us).
// One node/block; df f32 staged via global_load_lds (unmasked, clamped);
// w read directly from global (stream-once rows); agg written coalesced.
// LDS ~23 KB -> 7 blocks/CU.
// ---------------------------------------------------------------------------
__global__ __launch_bounds__(256, 7) void node_msg(
    const int* __restrict__ row_start,
    const int* __restrict__ dst_srt,
    const float* __restrict__ sh_srt,
    const unsigned short* __restrict__ w_srt,
    const float* __restrict__ st_vt32,
    float* __restrict__ agg)
{
    __shared__ __align__(16) float df[32 * 160];   // 20480 B (f32)
    __shared__ float aggbuf[480];
    __shared__ float sh_c[32][4];

    // chunked XCD remap (10000 = 8 * 1250)
    const int n   = (blockIdx.x & 7) * 1250 + (blockIdx.x >> 3);
    const int tid = threadIdx.x;
    const int p_start = row_start[n];
    const int p_end   = row_start[n + 1];

    const int tid2 = tid & 127;
    const int half = tid >> 7;
    int region, cb, iv;
    if (tid2 < 48)       { region = 0; cb = tid2 & 15;        iv = tid2 >> 4; }
    else if (tid2 < 64)  { region = 1; cb = tid2 - 48;        iv = 0; }
    else if (tid2 < 88)  { region = 2; cb = (tid2 - 64) & 7;  iv = (tid2 - 64) >> 3; }
    else if (tid2 < 112) { region = 3; cb = (tid2 - 88) & 7;  iv = (tid2 - 88) >> 3; }
    else if (tid2 < 120) { region = 4; cb = tid2 - 112;       iv = 0; }
    else                 { region = 5; cb = 0; iv = 0; }
    int rbase = 0, woff = 0, doff = 0;
    if (region == 0)      { rbase = 96 + iv * 64 + 4 * cb;  woff = 64 + 4 * cb;  doff = 4 * cb; }
    else if (region == 1) { rbase = 4 * cb;                 woff = 4 * cb;       doff = 4 * cb; }
    else if (region == 2) { rbase = 288 + iv * 32 + 4 * cb; woff = 128 + 4 * cb; doff = 64 + iv * 32 + 4 * cb; }
    else if (region == 3) { rbase = 384 + iv * 32 + 4 * cb; woff = 192 + 4 * cb; }
    else if (region == 4) { rbase = 64 + 4 * cb;            woff = 160 + 4 * cb; }
    int i1 = iv + 1; if (i1 == 3) i1 = 0;
    int i2 = 3 - iv - i1;

    f32x4 acc = {0.f, 0.f, 0.f, 0.f};

    for (int pb = p_start; pb < p_end; pb += 32) {
        __syncthreads();                       // df/sh_c reuse guard

        if (tid < 32) {
            int pp = min(pb + tid, p_end - 1);
            *reinterpret_cast<f32x4*>(&sh_c[tid][0]) =
                *reinterpret_cast<const f32x4*>(&sh_srt[(size_t)pp * 4]);
        }
        // stage df f32: 1280 x 16B (5 full rounds of 256, clamped)
        #pragma unroll
        for (int r = 0; r < 5; ++r) {
            int idx = tid + r * 256;
            int el = idx / 40, off = idx - el * 40;
            int pp = min(pb + el, p_end - 1);
            int d = dst_srt[pp];
            gl_lds16(st_vt32 + (size_t)d * 160 + off * 4, &df[idx * 4]);
        }
        __syncthreads();                       // vmcnt drained

        const int nvalid = p_end - pb;
        if (region < 5) {
            const int e0l = half * 16;
            #pragma unroll 4
            for (int j2 = 0; j2 < 16; ++j2) {
                int el = e0l + j2;
                if (el >= nvalid) break;       // uniform per half
                const float* dfp = &df[el * 160];
                const unsigned short* we = w_srt + (size_t)(pb + el) * 224;  // GLOBAL
                b16x4 w = *reinterpret_cast<const b16x4*>(we + woff);
                if (region == 0) {
                    f32x4 x = *reinterpret_cast<const f32x4*>(dfp + doff);
                    float sh = sh_c[el][iv];
                    #pragma unroll
                    for (int j = 0; j < 4; ++j)
                        acc[j] += b2f((unsigned short)w[j]) * x[j] * sh;
                } else if (region == 1 || region == 2) {
                    f32x4 x = *reinterpret_cast<const f32x4*>(dfp + doff);
                    #pragma unroll
                    for (int j = 0; j < 4; ++j)
                        acc[j] += b2f((unsigned short)w[j]) * x[j];
                } else if (region == 3) {
                    f32x4 xA = *reinterpret_cast<const f32x4*>(dfp + 64 + i1 * 32 + 4 * cb);
                    f32x4 xB = *reinterpret_cast<const f32x4*>(dfp + 64 + i2 * 32 + 4 * cb);
                    float shA = sh_c[el][i1], shB = sh_c[el][i2];
                    #pragma unroll
                    for (int j = 0; j < 4; ++j)
                        acc[j] += b2f((unsigned short)w[j]) *
                                  (xA[j] * shB - xB[j] * shA) * INV_SQRT2F;
                } else {
                    f32x4 x0 = *reinterpret_cast<const f32x4*>(dfp + 64 + 4 * cb);
                    f32x4 x1 = *reinterpret_cast<const f32x4*>(dfp + 96 + 4 * cb);
                    f32x4 x2 = *reinterpret_cast<const f32x4*>(dfp + 128 + 4 * cb);
                    float s0 = sh_c[el][0], s1 = sh_c[el][1], s2 = sh_c[el][2];
                    #pragma unroll
                    for (int j = 0; j < 4; ++j)
                        acc[j] += b2f((unsigned short)w[j]) *
                                  (x0[j] * s0 + x1[j] * s1 + x2[j] * s2) * INV_SQRT3F;
                }
            }
        }
    }

    // combine halves into aggbuf, write agg coalesced
    __syncthreads();
    if (half == 0 && region < 5) {
        #pragma unroll
        for (int j = 0; j < 4; ++j) aggbuf[rbase + j] = acc[j];
    }
    __syncthreads();
    if (half == 1 && region < 5) {
        #pragma unroll
        for (int j = 0; j < 4; ++j) aggbuf[rbase + j] += acc[j];
    }
    __syncthreads();
    if (tid < 120) {
        *reinterpret_cast<f32x4*>(&agg[(size_t)n * 480 + tid * 4]) =
            *reinterpret_cast<const f32x4*>(&aggbuf[tid * 4]);
    }
}

// ---------------------------------------------------------------------------
// Kernel C: out_gemm. 32 nodes/block, MFMA K=160 fused output transforms,
// then silu/sigmoid-gate epilogue, final out[n][160].
// ---------------------------------------------------------------------------
__global__ __launch_bounds__(256) void out_gemm(
    const float* __restrict__ agg,
    const float* __restrict__ nf,
    const unsigned short* __restrict__ WsCombT,
    const unsigned short* __restrict__ WvCombT,
    float* __restrict__ out)
{
    __shared__ float os_l[32][96];       // 12 KB
    __shared__ float ov_l[3][32][32];    // 12 KB

    const int n0  = blockIdx.x * 32;
    const int tid = threadIdx.x;
    const int lane = tid & 63;
    const int wv   = tid >> 6;
    const int l15  = lane & 15;
    const int g    = lane >> 4;

    #pragma unroll
    for (int jj = 0; jj < 6; ++jj) {
        int job = wv * 6 + jj;          // 0..23
        bool isS;
        int mt, nt, ii = 0;
        if (job < 12) { isS = true;  mt = job & 1; nt = job >> 1; }
        else { int j = job - 12; isS = false; ii = j >> 2; mt = (j >> 1) & 1; nt = j & 1; }

        int ra = mt * 16 + l15;
        int n  = min(n0 + ra, N_NODES - 1);
        const float* aggn = agg + (size_t)n * 480;
        const float* nfn  = nf + (size_t)n * 160;
        const unsigned short* WT = isS ? WsCombT : WvCombT;

        f32x4 c4 = {0.f, 0.f, 0.f, 0.f};
        #pragma unroll
        for (int kk = 0; kk < 5; ++kk) {
            int k0 = kk * 32 + g * 8;
            float av[8];
            if (isS) {
                if (k0 < 96) {
                    f32x4 p0 = *reinterpret_cast<const f32x4*>(aggn + k0);
                    f32x4 p1 = *reinterpret_cast<const f32x4*>(aggn + k0 + 4);
                    #pragma unroll
                    for (int j = 0; j < 4; ++j) { av[j] = p0[j] * (1.f/32.f); av[4+j] = p1[j] * (1.f/32.f); }
                } else {
                    f32x4 p0 = *reinterpret_cast<const f32x4*>(nfn + (k0 - 96));
                    f32x4 p1 = *reinterpret_cast<const f32x4*>(nfn + (k0 - 96) + 4);
                    #pragma unroll
                    for (int j = 0; j < 4; ++j) { av[j] = p0[j]; av[4+j] = p1[j]; }
                }
            } else {
                if (k0 < 128) {
                    int base = (k0 < 64) ? (96 + ii * 64 + k0)
                             : (k0 < 96) ? (288 + ii * 32 + (k0 - 64))
                                         : (384 + ii * 32 + (k0 - 96));
                    f32x4 p0 = *reinterpret_cast<const f32x4*>(aggn + base);
                    f32x4 p1 = *reinterpret_cast<const f32x4*>(aggn + base + 4);
                    #pragma unroll
                    for (int j = 0; j < 4; ++j) { av[j] = p0[j] * (1.f/32.f); av[4+j] = p1[j] * (1.f/32.f); }
                } else {
                    #pragma unroll
                    for (int j = 0; j < 8; ++j)
                        av[j] = nfn[64 + (k0 - 128 + j) * 3 + ii];
                }
            }
            bf16x8 a;
            #pragma unroll
            for (int j = 0; j < 8; ++j) a[j] = (short)f2b(av[j]);
            bf16x8 bfr = *reinterpret_cast<const bf16x8*>(
                WT + (size_t)(nt * 16 + l15) * 160 + k0);
            c4 = __builtin_amdgcn_mfma_f32_16x16x32_bf16(a, bfr, c4, 0, 0, 0);
        }
        #pragma unroll
        for (int r = 0; r < 4; ++r) {
            int row = mt * 16 + g * 4 + r;
            int col = nt * 16 + l15;
            if (isS) os_l[row][col] = c4[r];
            else     ov_l[ii][row][col] = c4[r];
        }
    }
    __syncthreads();

    for (int idx = tid; idx < 32 * 160; idx += 256) {
        int r = idx / 160, c = idx - r * 160;
        int n = n0 + r;
        if (n < N_NODES) {
            if (c < 64) {
                float x = os_l[r][c];
                out[(size_t)n * 160 + c] = x / (1.f + expf(-x));      // silu
            } else {
                int t = c - 64;
                int k = t / 3, i = t - 3 * k;
                float gg = os_l[r][64 + k];
                gg = 1.f / (1.f + expf(-gg));                          // sigmoid
                out[(size_t)n * 160 + c] = gg * ov_l[i][r][k];
            }
        }
    }
}

// ---------------------------------------------------------------------------
// Fallback path (only if ws can't hold w_srt): fused kernel + out.
// ---------------------------------------------------------------------------
__global__ __launch_bounds__(256, 3) void edge_conv_fused(
    const unsigned short* __restrict__ W1T,
    const unsigned short* __restrict__ W2T,
    const int* __restrict__ order,
    const int* __restrict__ src_srt,
    const int* __restrict__ dst_srt,
    const float* __restrict__ sh_srt,
    const float* __restrict__ edge_feature,
    const unsigned short* __restrict__ st_vt16,
    float* __restrict__ agg)
{
    __shared__ __align__(16) unsigned short A1[32 * 64];
    __shared__ __align__(16) unsigned short Hs[32 * 64];
    __shared__ __align__(16) unsigned short w_s[32 * 224];
    __shared__ __align__(16) unsigned short df[2][32 * 160];
    __shared__ int   eid_s[32 * TILES];
    __shared__ int   src_s[32 * TILES];
    __shared__ int   dst_s[32 * TILES];
    __shared__ float sh_s[32 * TILES][4];

    const int tid  = threadIdx.x;
    const int lane = tid & 63;
    const int wv   = tid >> 6;
    const int l15  = lane & 15;
    const int g    = lane >> 4;
    const int p0   = blockIdx.x * (32 * TILES);

    bf16x8 w1b0 = *reinterpret_cast<const bf16x8*>(&W1T[(wv * 16 + l15) * 64 + g * 8]);
    bf16x8 w1b1 = *reinterpret_cast<const bf16x8*>(&W1T[(wv * 16 + l15) * 64 + 32 + g * 8]);
    bf16x8 w2b0[4], w2b1[4];
    #pragma unroll
    for (int ii = 0; ii < 4; ++ii) {
        int nt = wv * 4 + ii;
        w2b0[ii] = *reinterpret_cast<const bf16x8*>(&W2T[(nt * 16 + l15) * 64 + g * 8]);
        w2b1[ii] = *reinterpret_cast<const bf16x8*>(&W2T[(nt * 16 + l15) * 64 + 32 + g * 8]);
    }

    for (int b = tid; b < 32 * TILES; b += 256) {
        int p = p0 + b;
        eid_s[b] = order[p];
        src_s[b] = src_srt[p];
        dst_s[b] = dst_srt[p];
        *reinterpret_cast<f32x4*>(&sh_s[b][0]) =
            *reinterpret_cast<const f32x4*>(&sh_srt[(size_t)p * 4]);
    }
    __syncthreads();

    const int tid2 = tid & 127;
    int region, cb, iv;
    if (tid2 < 48)       { region = 0; cb = tid2 & 15;        iv = tid2 >> 4; }
    else if (tid2 < 64)  { region = 1; cb = tid2 - 48;        iv = 0; }
    else if (tid2 < 88)  { region = 2; cb = (tid2 - 64) & 7;  iv = (tid2 - 64) >> 3; }
    else if (tid2 < 112) { region = 3; cb = (tid2 - 88) & 7;  iv = (tid2 - 88) >> 3; }
    else if (tid2 < 120) { region = 4; cb = tid2 - 112;       iv = 0; }
    else                 { region = 5; cb = 0; iv = 0; }
    int rbase = 0, woff = 0, doff = 0;
    if (region == 0)      { rbase = 96 + iv * 64 + 4 * cb;  woff = 64 + 4 * cb;  doff = 4 * cb; }
    else if (region == 1) { rbase = 4 * cb;                 woff = 4 * cb;       doff = 4 * cb; }
    else if (region == 2) { rbase = 288 + iv * 32 + 4 * cb; woff = 128 + 4 * cb; doff = 64 + iv * 32 + 4 * cb; }
    else if (region == 3) { rbase = 384 + iv * 32 + 4 * cb; woff = 192 + 4 * cb; }
    else if (region == 4) { rbase = 64 + 4 * cb;            woff = 160 + 4 * cb; }
    int i1 = iv + 1; if (i1 == 3) i1 = 0;
    int i2 = 3 - iv - i1;

    f32x4 acc = {0.f, 0.f, 0.f, 0.f};
    int cur = src_s[(tid >> 7) * 16];

    f32x4 efr[2];
    auto load_ef = [&](int t) {
        int ebase = t * 32;
        #pragma unroll
        for (int r = 0; r < 2; ++r) {
            int q = tid + r * 256;
            int el = q >> 4, qf = q & 15;
            efr[r] = *reinterpret_cast<const f32x4*>(
                edge_feature + (size_t)eid_s[ebase + el] * 64 + qf * 4);
        }
    };
    auto write_ef = [&]() {
        #pragma unroll
        for (int r = 0; r < 2; ++r) {
            int q = tid + r * 256;
            int el = q >> 4, f0 = (q & 15) * 4;
            b16x4 h;
            #pragma unroll
            for (int j = 0; j < 4; ++j) h[j] = (short)f2b(efr[r][j]);
            *reinterpret_cast<b16x4*>(&A1[el * 64 + (f0 ^ ((el & 7) << 3))]) = h;
        }
    };
    auto issue_df = [&](int t, int b) {
        int ebase = t * 32;
        #pragma unroll
        for (int r = 0; r < 3; ++r) {
            int idx = tid + r * 256;
            if (idx < 640) {
                int el = idx / 20, off = idx - el * 20;
                gl_lds16(st_vt16 + (size_t)dst_s[ebase + el] * 160 + off * 8,
                         &df[b][idx * 8]);
            }
        }
    };

    issue_df(0, 0);
    load_ef(0);

    for (int t = 0; t < TILES; ++t) {
        const int b = t & 1;
        write_ef();
        __syncthreads();
        if (t < TILES - 1) {
            issue_df(t + 1, b ^ 1);
            load_ef(t + 1);
        }
        {
            const int nt = wv;
            #pragma unroll
            for (int mt = 0; mt < 2; ++mt) {
                f32x4 c4 = {0.f, 0.f, 0.f, 0.f};
                int ra = mt * 16 + l15;
                int sw = (ra & 7) << 3;
                bf16x8 a0 = *reinterpret_cast<const bf16x8*>(&A1[ra * 64 + ((g * 8) ^ sw)]);
                bf16x8 a1 = *reinterpret_cast<const bf16x8*>(&A1[ra * 64 + ((32 + g * 8) ^ sw)]);
                c4 = __builtin_amdgcn_mfma_f32_16x16x32_bf16(a0, w1b0, c4, 0, 0, 0);
                c4 = __builtin_amdgcn_mfma_f32_16x16x32_bf16(a1, w1b1, c4, 0, 0, 0);
                #pragma unroll
                for (int r = 0; r < 4; ++r) {
                    int row = mt * 16 + g * 4 + r;
                    int col = nt * 16 + l15;
                    Hs[row * 64 + (col ^ ((row & 7) << 3))] = f2b(fmaxf(c4[r], 0.f));
                }
            }
        }
        __syncthreads();
        {
            #pragma unroll
            for (int ii = 0; ii < 4; ++ii) {
                int nt = wv * 4 + ii;
                #pragma unroll
                for (int mt = 0; mt < 2; ++mt) {
                    f32x4 c4 = {0.f, 0.f, 0.f, 0.f};
                    int ra = mt * 16 + l15;
                    int sw = (ra & 7) << 3;
                    bf16x8 a0 = *reinterpret_cast<const bf16x8*>(&Hs[ra * 64 + ((g * 8) ^ sw)]);
                    bf16x8 a1 = *reinterpret_cast<const bf16x8*>(&Hs[ra * 64 + ((32 + g * 8) ^ sw)]);
                    c4 = __builtin_amdgcn_mfma_f32_16x16x32_bf16(a0, w2b0[ii], c4, 0, 0, 0);
                    c4 = __builtin_amdgcn_mfma_f32_16x16x32_bf16(a1, w2b1[ii], c4, 0, 0, 0);
                    if (nt < 14) {
                        #pragma unroll
                        for (int r = 0; r < 4; ++r) {
                            int row = mt * 16 + g * 4 + r;
                            w_s[row * 224 + nt * 16 + l15] = f2b(c4[r]);
                        }
                    }
                }
            }
        }
        __syncthreads();
        if (region < 5) {
            const int e0l = (tid >> 7) * 16;
            #pragma unroll 4
            for (int j2 = 0; j2 < 16; ++j2) {
                int el = e0l + j2;
                int eg = t * 32 + el;
                int s = src_s[eg];
                if (s != cur) {
                    #pragma unroll
                    for (int j = 0; j < 4; ++j)
                        atomicAdd(&agg[(size_t)cur * 480 + rbase + j], acc[j]);
                    acc = (f32x4){0.f, 0.f, 0.f, 0.f};
                    cur = s;
                }
                const unsigned short* dfp = &df[b][el * 160];
                const unsigned short* we  = &w_s[el * 224];
                b16x4 w = *reinterpret_cast<const b16x4*>(we + woff);
                if (region == 0) {
                    b16x4 x = *reinterpret_cast<const b16x4*>(dfp + doff);
                    float sh = sh_s[eg][iv];
                    #pragma unroll
                    for (int j = 0; j < 4; ++j)
                        acc[j] += b2f((unsigned short)w[j]) * b2f((unsigned short)x[j]) * sh;
                } else if (region == 1 || region == 2) {
                    b16x4 x = *reinterpret_cast<const b16x4*>(dfp + doff);
                    #pragma unroll
                    for (int j = 0; j < 4; ++j)
                        acc[j] += b2f((unsigned short)w[j]) * b2f((unsigned short)x[j]);
                } else if (region == 3) {
                    b16x4 xA = *reinterpret_cast<const b16x4*>(dfp + 64 + i1 * 32 + 4 * cb);
                    b16x4 xB = *reinterpret_cast<const b16x4*>(dfp + 64 + i2 * 32 + 4 * cb);
                    float shA = sh_s[eg][i1], shB = sh_s[eg][i2];
                    #pragma unroll
                    for (int j = 0; j < 4; ++j)
                        acc[j] += b2f((unsigned short)w[j]) *
                                  (b2f((unsigned short)xA[j]) * shB -
                                   b2f((unsigned short)xB[j]) * shA) * INV_SQRT2F;
                } else {
                    b16x4 x0 = *reinterpret_cast<const b16x4*>(dfp + 64 + 4 * cb);
                    b16x4 x1 = *reinterpret_cast<const b16x4*>(dfp + 96 + 4 * cb);
                    b16x4 x2 = *reinterpret_cast<const b16x4*>(dfp + 128 + 4 * cb);
                    float s0 = sh_s[eg][0], s1 = sh_s[eg][1], s2 = sh_s[eg][2];
                    #pragma unroll
                    for (int j = 0; j < 4; ++j)
                        acc[j] += b2f((unsigned short)w[j]) *
                                  (b2f((unsigned short)x0[j]) * s0 +
                                   b2f((unsigned short)x1[j]) * s1 +
                                   b2f((unsigned short)x2[j]) * s2) * INV_SQRT3F;
                }
            }
        }
    }
    if (region < 5) {
        #pragma unroll
        for (int j = 0; j < 4; ++j)
            atomicAdd(&agg[(size_t)cur * 480 + rbase + j], acc[j]);
    }
}

__global__ __launch_bounds__(128) void out_kernel(
    const float* __restrict__ agg,
    const float* __restrict__ nf,
    const float* __restrict__ Wskip0,
    const float* __restrict__ Wskip1,
    const float* __restrict__ Wout_s,
    const float* __restrict__ Wout_v,
    float* __restrict__ out)
{
    __shared__ float aggl[480];
    __shared__ float os_s[96];
    const int n = blockIdx.x;
    const int tid = threadIdx.x;
    const float* nfn = nf + (size_t)n * 160;

    for (int idx = tid; idx < 480; idx += 128)
        aggl[idx] = agg[(size_t)n * 480 + idx] * (1.f / 32.f);
    __syncthreads();

    if (tid < 96) {
        float acc = 0.f;
        #pragma unroll 8
        for (int k = 0; k < 64; ++k) acc += nfn[k] * Wskip0[k * 96 + tid];
        for (int r = 0; r < 96; ++r) acc += aggl[r] * Wout_s[r * 96 + tid];
        os_s[tid] = acc;
    }
    __syncthreads();

    if (tid < 64) {
        float x = os_s[tid];
        out[(size_t)n * 160 + tid] = x / (1.f + expf(-x));
    }
    if (tid < 96) {
        int t = tid;
        int k = t / 3, i = t - 3 * k;
        float acc = 0.f;
        #pragma unroll 8
        for (int m = 0; m < 32; ++m) acc += nfn[64 + m * 3 + i] * Wskip1[m * 32 + k];
        #pragma unroll 8
        for (int m = 0; m < 64; ++m) acc += aggl[96 + i * 64 + m] * Wout_v[m * 32 + k];
        #pragma unroll 8
        for (int m = 0; m < 32; ++m) acc += aggl[288 + i * 32 + m] * Wout_v[(64 + m) * 32 + k];
        #pragma unroll 8
        for (int m = 0; m < 32; ++m) acc += aggl[384 + i * 32 + m] * Wout_v[(96 + m) * 32 + k];
        float g = os_s[64 + k];
        g = 1.f / (1.f + expf(-g));
        out[(size_t)n * 160 + 64 + t] = g * acc;
    }
}

// ---------------------------------------------------------------------------
extern "C" void kernel_launch(void* const* d_in, const int* in_sizes, int n_in,
                              void* d_out, int out_size, void* d_ws, size_t ws_size,
                              hipStream_t stream)
{
    const float* nf     = (const float*)d_in[0];
    const float* ea     = (const float*)d_in[1];
    const float* ef     = (const float*)d_in[2];
    const float* Wskip0 = (const float*)d_in[3];
    const float* Wskip1 = (const float*)d_in[4];
    const float* Wnl0   = (const float*)d_in[5];
    const float* Wnl1   = (const float*)d_in[6];
    const float* Wfc1   = (const float*)d_in[7];
    const float* Wfc2   = (const float*)d_in[8];
    const float* Wout_s = (const float*)d_in[9];
    const float* Wout_v = (const float*)d_in[10];
    const int*   eidx   = (const int*)d_in[11];
    float* out = (float*)d_out;

    // workspace layout (16B-aligned sections)
    int*   cnt       = (int*)d_ws;                        // 10000
    int*   fill      = cnt + 10000;                       // 10000
    int*   row_start = fill + 10000;                      // 10004
    int*   order     = row_start + 10004;                 // 320000
    int*   src_srt   = order + 320000;                    // 320000
    int*   dst_srt   = src_srt + 320000;                  // 320000
    float* sh_srt    = (float*)(dst_srt + 320000);        // 1,280,000
    float* agg       = sh_srt + 1280000;                  // 4,800,000
    float* st_vt32   = agg + 4800000;                     // 1,600,000
    unsigned short* st_vt16 = (unsigned short*)(st_vt32 + 1600000); // 1,600,000
    unsigned short* W1T     = st_vt16 + 1600000;          // 4,096
    unsigned short* W2T     = W1T + 4096;                 // 16,384
    unsigned short* WsCombT = W2T + 16384;                // 15,360
    unsigned short* WvCombT = WsCombT + 15360;            // 5,120 (+pad 32)
    unsigned short* w_srt   = WvCombT + 5152;             // (N_EDGES+32)*224

    const size_t need_split =
        (size_t)((const char*)(w_srt + (size_t)(N_EDGES + 32) * 224) - (const char*)d_ws);
    const bool use_split = (ws_size >= need_split);

    hipMemsetAsync(cnt, 0, 20000 * sizeof(int), stream);   // cnt+fill

    prep_kernel<<<1715, 256, 0, stream>>>(
        nf, Wnl0, Wnl1, Wfc1, Wfc2, Wout_s, Wout_v, Wskip0, Wskip1,
        eidx, st_vt32, st_vt16, W1T, W2T, WsCombT, WvCombT, cnt);

    scan_kernel<<<1, 1024, 0, stream>>>(cnt, row_start);
    scatter_kernel<<<(N_EDGES + 255) / 256, 256, 0, stream>>>(
        eidx, ea, row_start, fill, order, src_srt, dst_srt, sh_srt);

    if (use_split) {
        edge_mlp<<<NBLK, 256, 0, stream>>>(W1T, W2T, order, ef, w_srt);
        node_msg<<<N_NODES, 256, 0, stream>>>(
            row_start, dst_srt, sh_srt, w_srt, st_vt32, agg);
        out_gemm<<<(N_NODES + 31) / 32, 256, 0, stream>>>(
            agg, nf, WsCombT, WvCombT, out);
    } else {
        hipMemsetAsync(agg, 0, (size_t)N_NODES * 480 * sizeof(float), stream);
        edge_conv_fused<<<NBLK, 256, 0, stream>>>(
            W1T, W2T, order, src_srt, dst_srt, sh_srt, ef, st_vt16, agg);
        out_kernel<<<N_NODES, 128, 0, stream>>>(
            agg, nf, Wskip0, Wskip1, Wout_s, Wout_v, out);
    }
}